// Round 7
// baseline (196.406 us; speedup 1.0000x reference)
//
#include <hip/hip_runtime.h>
#include <math.h>

#define N 8192
#define C 10
#define NUM_ITERS 5
#define FBLOCK 1024        /* 16 waves, 1 block/CU (128KB LDS), 4 waves/SIMD */
#define IBLK 64            /* i's per block */
#define NIB (N / IBLK)     /* 128 i-blocks; grid = 256 = 128 ib x 2 jc */
#define JHALF (N / 2)      /* 4096 j's per jc half */
#define JSLICE (JHALF / 16)/* 256 j's per wave */
#define NS (JSLICE / 32)   /* 8 s-iters per wave */
#define LOG2E 1.44269504088896340736f
#define C3 (LOG2E / 64.0f)

typedef _Float16 half8 __attribute__((ext_vector_type(8)));
typedef _Float16 half4 __attribute__((ext_vector_type(4)));
typedef _Float16 half2 __attribute__((ext_vector_type(2)));
typedef float f32x4 __attribute__((ext_vector_type(4)));

// ws layout:
//   ajs  half8[N]    128KB : j-side spatial aug [f*C3 x3, 0, 0,0,-h3*C3, 1]
//   ajb  half8[N]    128KB : j-side bilateral aug [f*L2E x6, -h6*L2E, 1]
//   pf0  f16[16][N]  256KB : softmax probs (ping), rows 10..15 zero
//   pf1  f16[16][N]  256KB : softmax probs (pong), rows 10..15 zero
//   part f32[128][2048] 1MB : jc=1 partial dumps
//   flags u32[5][128]      : per-iteration pair handshake
#define WS_AJS 0
#define WS_AJB (128 * 1024)
#define WS_PF0 (256 * 1024)
#define WS_PF1 (512 * 1024)
#define WS_PART (768 * 1024)
#define WS_FLAGS (WS_PART + 128 * 2048 * 4)

static __device__ __forceinline__ half4 expcvt(f32x4 d) {
    float e0 = __builtin_amdgcn_exp2f(d[0]);
    float e1 = __builtin_amdgcn_exp2f(d[1]);
    float e2 = __builtin_amdgcn_exp2f(d[2]);
    float e3 = __builtin_amdgcn_exp2f(d[3]);
    half2 lo = __builtin_bit_cast(half2, __builtin_amdgcn_cvt_pkrtz(e0, e1));
    half2 hi = __builtin_bit_cast(half2, __builtin_amdgcn_cvt_pkrtz(e2, e3));
    half4 r = {lo[0], lo[1], hi[0], hi[1]};
    return r;
}

// per (filter, jsub) chunk: GEMM1 (4 isub) -> exp -> GEMM2 accumulate.
// B1/ACC arrays indexed with literals only (stay in registers).
#define CHUNK(AF, PF_, B1, ACC)                                                   \
    {                                                                             \
        f32x4 _d0 = __builtin_amdgcn_mfma_f32_16x16x16f16(AF, B1[0], zero, 0, 0, 0); \
        f32x4 _d1 = __builtin_amdgcn_mfma_f32_16x16x16f16(AF, B1[1], zero, 0, 0, 0); \
        f32x4 _d2 = __builtin_amdgcn_mfma_f32_16x16x16f16(AF, B1[2], zero, 0, 0, 0); \
        f32x4 _d3 = __builtin_amdgcn_mfma_f32_16x16x16f16(AF, B1[3], zero, 0, 0, 0); \
        half4 _w0 = expcvt(_d0), _w1 = expcvt(_d1), _w2 = expcvt(_d2), _w3 = expcvt(_d3); \
        ACC[0] = __builtin_amdgcn_mfma_f32_16x16x16f16(_w0, PF_, ACC[0], 0, 0, 0);   \
        ACC[1] = __builtin_amdgcn_mfma_f32_16x16x16f16(_w1, PF_, ACC[1], 0, 0, 0);   \
        ACC[2] = __builtin_amdgcn_mfma_f32_16x16x16f16(_w2, PF_, ACC[2], 0, 0, 0);   \
        ACC[3] = __builtin_amdgcn_mfma_f32_16x16x16f16(_w3, PF_, ACC[3], 0, 0, 0);   \
    }

// once per launch: aug features + softmax(unaries) -> pf0; zero rows 10..15; zero flags
__global__ __launch_bounds__(256) void init_kernel(
    const float* __restrict__ unaries, const float* __restrict__ feat,
    half8* __restrict__ ajs8, half8* __restrict__ ajb8,
    _Float16* __restrict__ pf0, _Float16* __restrict__ pf1,
    unsigned int* __restrict__ flags) {
    int n = blockIdx.x * 256 + threadIdx.x;
    if (blockIdx.x == 0 && threadIdx.x < NUM_ITERS * NIB) flags[threadIdx.x] = 0u;
    float f6[6];
#pragma unroll
    for (int d = 0; d < 6; ++d) f6[d] = feat[d * N + n];
    float h3 = 0.5f * (f6[0] * f6[0] + f6[1] * f6[1] + f6[2] * f6[2]);
    float h6v = h3 + 0.5f * (f6[3] * f6[3] + f6[4] * f6[4] + f6[5] * f6[5]);
    half8 a = {};
    a[0] = (_Float16)(f6[0] * C3);
    a[1] = (_Float16)(f6[1] * C3);
    a[2] = (_Float16)(f6[2] * C3);
    a[6] = (_Float16)(-h3 * C3);
    a[7] = (_Float16)1.0f;
    ajs8[n] = a;
    half8 b;
#pragma unroll
    for (int d = 0; d < 6; ++d) b[d] = (_Float16)(f6[d] * LOG2E);
    b[6] = (_Float16)(-h6v * LOG2E);
    b[7] = (_Float16)1.0f;
    ajb8[n] = b;

    float q[C];
#pragma unroll
    for (int c = 0; c < C; ++c) q[c] = unaries[c * N + n];
    float m = q[0];
#pragma unroll
    for (int c = 1; c < C; ++c) m = fmaxf(m, q[c]);
    float e[C], s = 0.0f;
#pragma unroll
    for (int c = 0; c < C; ++c) {
        e[c] = __builtin_amdgcn_exp2f((q[c] - m) * LOG2E);
        s += e[c];
    }
    float inv = 1.0f / s;
#pragma unroll
    for (int c = 0; c < C; ++c) pf0[c * N + n] = (_Float16)(e[c] * inv);
#pragma unroll
    for (int c = C; c < 16; ++c) {
        pf0[c * N + n] = (_Float16)0.0f;
        pf1[c * N + n] = (_Float16)0.0f;
    }
}

// one dispatch per CRF iteration. 256 blocks = 128 ib x 2 jc, 1 block/CU
// (co-resident). Block (ib,jc): 64 i's vs 4096 j's. ajs/ajb staged ONCE in
// LDS (128KB, no main-loop barriers); pf fetched from L2 (1-deep prefetch).
// jc=1 publishes partials via release-store flag; jc=0 combines + softmax.
__global__ __launch_bounds__(FBLOCK, 4) void fused_kernel(
    const float* __restrict__ unaries, const float* __restrict__ feat,
    const float* __restrict__ SW, const float* __restrict__ BW,
    const float* __restrict__ CM,
    const float4* __restrict__ ajs_f4, const float4* __restrict__ ajb_f4,
    const _Float16* __restrict__ pf_in, _Float16* __restrict__ pf_out,
    float* __restrict__ part, unsigned int* __restrict__ flags,
    float* __restrict__ out, int is_last, int it) {
    __shared__ union {
        struct { half4 ajs_l[JHALF * 2]; half4 ajb_l[JHALF * 2]; } s;  // 128 KB
        float rbuf[16 * 2048];                                          // 128 KB
    } sm;
    int t = threadIdx.x;
    int ib = blockIdx.x & (NIB - 1);
    int jc = blockIdx.x >> 7;
    int i0 = ib * IBLK;
    int jbase = jc * JHALF;
    int lane = t & 63;
    int w = t >> 6;
    int il = lane & 15;
    int quad = lane >> 4;
    int h = quad & 1;
    bool klo = (quad < 2);
    const half4 hz = {};
    const f32x4 zero = {0.f, 0.f, 0.f, 0.f};

    // ---- stage ajs/ajb (whole jc-half) into LDS once ----
    {
        const float4* s0 = ajs_f4 + jbase;
        const float4* s1 = ajb_f4 + jbase;
        float4* d0 = (float4*)sm.s.ajs_l;
        float4* d1 = (float4*)sm.s.ajb_l;
#pragma unroll
        for (int k = 0; k < 4; ++k) {
            d0[k * 1024 + t] = s0[k * 1024 + t];
            d1[k * 1024 + t] = s1[k * 1024 + t];
        }
    }

    // ---- i-side B1 fragments: 4 subtiles x 2 filters ----
    half4 b1s[4], b1b[4];
#pragma unroll
    for (int su = 0; su < 4; ++su) {
        int i = i0 + su * 16 + il;
        float g0 = feat[0 * N + i], g1 = feat[1 * N + i], g2 = feat[2 * N + i];
        float g3 = feat[3 * N + i], g4 = feat[4 * N + i], g5 = feat[5 * N + i];
        float h3 = 0.5f * (g0 * g0 + g1 * g1 + g2 * g2);
        float h6v = h3 + 0.5f * (g3 * g3 + g4 * g4 + g5 * g5);
        half4 slo = {(_Float16)g0, (_Float16)g1, (_Float16)g2, (_Float16)0.0f};
        half4 shi = {(_Float16)0.0f, (_Float16)0.0f, (_Float16)1.0f, (_Float16)(-h3 * C3)};
        half4 blo = {(_Float16)g0, (_Float16)g1, (_Float16)g2, (_Float16)g3};
        half4 bhi = {(_Float16)g4, (_Float16)g5, (_Float16)1.0f, (_Float16)(-h6v * LOG2E)};
        b1s[su] = klo ? (h ? shi : slo) : hz;
        b1b[su] = klo ? (h ? bhi : blo) : hz;
    }
    __syncthreads();

    f32x4 acc_s[4] = {zero, zero, zero, zero};
    f32x4 acc_b[4] = {zero, zero, zero, zero};

    int wj = w * JSLICE;                               // wave's local j base
    const _Float16* prow = pf_in + il * N + jbase + wj;
    half4 cp0 = *(const half4*)&prow[quad * 4];
    half4 cp1 = *(const half4*)&prow[16 + quad * 4];

#pragma unroll 2
    for (int k = 0; k < NS; ++k) {
        int kn = (k + 1) & (NS - 1);                   // wrap: harmless reload
        half4 np0 = *(const half4*)&prow[kn * 32 + quad * 4];
        half4 np1 = *(const half4*)&prow[kn * 32 + 16 + quad * 4];
        int jl = wj + k * 32;
        half4 vs0 = sm.s.ajs_l[(jl + il) * 2 + h];
        half4 vs1 = sm.s.ajs_l[(jl + 16 + il) * 2 + h];
        half4 vb0 = sm.s.ajb_l[(jl + il) * 2 + h];
        half4 vb1 = sm.s.ajb_l[(jl + 16 + il) * 2 + h];
        // A-side garbage lanes (quad>=2) safe: B1 is exactly zero there.
        CHUNK(vs0, cp0, b1s, acc_s);
        CHUNK(vs1, cp1, b1s, acc_s);
        CHUNK(vb0, cp0, b1b, acc_b);
        CHUNK(vb1, cp1, b1b, acc_b);
        cp0 = np0;
        cp1 = np1;
    }

    // ---- cross-wave reduction (rbuf overlays staging; conflict-free dump) ----
    __syncthreads();
    {
        float* rb = sm.rbuf + w * 2048;
#pragma unroll
        for (int su = 0; su < 4; ++su)
#pragma unroll
            for (int r = 0; r < 4; ++r) {
                rb[(su * 8 + r) * 64 + lane]     = acc_s[su][r];
                rb[(su * 8 + 4 + r) * 64 + lane] = acc_b[su][r];
            }
    }
    __syncthreads();
#pragma unroll
    for (int rep = 0; rep < 2; ++rep) {
        int idx = rep * 1024 + t;
        float tot = 0.f;
#pragma unroll
        for (int w2 = 0; w2 < 16; ++w2) tot += sm.rbuf[w2 * 2048 + idx];
        sm.rbuf[idx] = tot;   // w2=0 slot: read/written only by this thread
    }
    __syncthreads();

    int fidx = it * NIB + ib;
    if (jc == 1) {
        // publish partials, release flag
        float* pg = part + (size_t)ib * 2048;
        pg[t] = sm.rbuf[t];
        pg[t + 1024] = sm.rbuf[t + 1024];
        __syncthreads();
        if (t == 0)
            __hip_atomic_store(&flags[fidx], 1u, __ATOMIC_RELEASE,
                               __HIP_MEMORY_SCOPE_AGENT);
        return;
    }
    // jc == 0: wait for partner, add partials
    if (t == 0) {
        while (__hip_atomic_load(&flags[fidx], __ATOMIC_ACQUIRE,
                                 __HIP_MEMORY_SCOPE_AGENT) == 0u)
            __builtin_amdgcn_s_sleep(16);
    }
    __syncthreads();
    {
        const float* pg = part + (size_t)ib * 2048;
        // atomic loads: read from device coherence point (cross-XCD safe)
        sm.rbuf[t] += __hip_atomic_load(&pg[t], __ATOMIC_RELAXED,
                                        __HIP_MEMORY_SCOPE_AGENT);
        sm.rbuf[t + 1024] += __hip_atomic_load(&pg[t + 1024], __ATOMIC_RELAXED,
                                               __HIP_MEMORY_SCOPE_AGENT);
    }
    __syncthreads();

    // ---- combine + compatibility + softmax for 64 i's ----
    if (t < IBLK) {
        int su = t >> 4, q = (t >> 2) & 3, r = t & 3;
        int i = i0 + su * 16 + q * 4 + r;
        float sp[C], bl[C];
#pragma unroll
        for (int c = 0; c < C; ++c) {
            sp[c] = sm.rbuf[(su * 8 + r) * 64 + q * 16 + c];
            bl[c] = sm.rbuf[(su * 8 + 4 + r) * 64 + q * 16 + c];
        }
        float msg[C];
#pragma unroll
        for (int c = 0; c < C; ++c) {
            float m = 0.f;
#pragma unroll
            for (int k = 0; k < C; ++k)
                m += SW[c * C + k] * sp[k] + BW[c * C + k] * bl[k];
            msg[c] = m;
        }
        float qq[C];
#pragma unroll
        for (int c = 0; c < C; ++c) {
            float pw = 0.f;
#pragma unroll
            for (int k = 0; k < C; ++k) pw += CM[c * C + k] * msg[k];
            qq[c] = unaries[c * N + i] - pw;
        }
        if (is_last) {
#pragma unroll
            for (int c = 0; c < C; ++c) out[c * N + i] = qq[c];
        } else {
            float m = qq[0];
#pragma unroll
            for (int c = 1; c < C; ++c) m = fmaxf(m, qq[c]);
            float e[C], s = 0.0f;
#pragma unroll
            for (int c = 0; c < C; ++c) {
                e[c] = __builtin_amdgcn_exp2f((qq[c] - m) * LOG2E);
                s += e[c];
            }
            float inv = 1.0f / s;
#pragma unroll
            for (int c = 0; c < C; ++c) pf_out[c * N + i] = (_Float16)(e[c] * inv);
        }
    }
}

extern "C" void kernel_launch(void* const* d_in, const int* in_sizes, int n_in,
                              void* d_out, int out_size, void* d_ws, size_t ws_size,
                              hipStream_t stream) {
    const float* unaries = (const float*)d_in[0];   // [10, 8192]
    const float* feat    = (const float*)d_in[1];   // [6, 8192]
    const float* SW      = (const float*)d_in[2];   // [10,10]
    const float* BW      = (const float*)d_in[3];   // [10,10]
    const float* CM      = (const float*)d_in[4];   // [10,10]
    float* out = (float*)d_out;

    char* ws = (char*)d_ws;
    half8* ajs    = (half8*)(ws + WS_AJS);
    half8* ajb    = (half8*)(ws + WS_AJB);
    _Float16* pf0 = (_Float16*)(ws + WS_PF0);
    _Float16* pf1 = (_Float16*)(ws + WS_PF1);
    float* part   = (float*)(ws + WS_PART);
    unsigned int* flags = (unsigned int*)(ws + WS_FLAGS);

    init_kernel<<<N / 256, 256, 0, stream>>>(unaries, feat, ajs, ajb, pf0, pf1, flags);
    const _Float16* pin = pf0;
    _Float16* pout = pf1;
    for (int it = 0; it < NUM_ITERS; ++it) {
        fused_kernel<<<2 * NIB, FBLOCK, 0, stream>>>(
            unaries, feat, SW, BW, CM, (const float4*)ajs, (const float4*)ajb,
            pin, pout, part, flags, out, it == NUM_ITERS - 1 ? 1 : 0, it);
        const _Float16* tmp = pout;
        pout = (_Float16*)pin;
        pin = tmp;
    }
}

// Round 8
// 167.239 us; speedup vs baseline: 1.1744x; 1.1744x over previous
//
#include <hip/hip_runtime.h>
#include <math.h>

#define N 8192
#define C 10
#define NUM_ITERS 5
#define FBLOCK 1024        /* 16 waves, 1 block/CU, 4 waves/SIMD, VGPR<=128 */
#define IBLK 32            /* i's per block */
#define NBLK (N / IBLK)    /* 256 blocks = 1 per CU */
#define JW (N / 16)        /* 512 j's per wave (contiguous slice) */
#define NS (JW / 32)       /* 16 s-iters per wave, 32 j's each */
#define LOG2E 1.44269504088896340736f
#define C3 (LOG2E / 64.0f)

typedef _Float16 half8 __attribute__((ext_vector_type(8)));
typedef _Float16 half4 __attribute__((ext_vector_type(4)));
typedef _Float16 half2 __attribute__((ext_vector_type(2)));
typedef float f32x4 __attribute__((ext_vector_type(4)));

// ws layout:
//   ajs half8[N]        128KB : j-side spatial aug [f*C3 x3, 0, 0,0,-h3*C3, 1]
//   ajb half8[N]        128KB : j-side bilateral aug [f*L2E x6, -h6*L2E, 1]
//   pf0 f16[N/16][16][16] 256KB : probs, J-TILED (tile jt, row c, col j&15); rows 10..15 zero
//   pf1 f16[N/16][16][16] 256KB : ping-pong partner
#define WS_AJS 0
#define WS_AJB (N * 16)
#define WS_PF0 (N * 32)
#define WS_PF1 (N * 64)
#define PFIDX(n, c) ((((n) >> 4) * 16 + (c)) * 16 + ((n) & 15))

static __device__ __forceinline__ half4 expcvt(f32x4 d) {
    float e0 = __builtin_amdgcn_exp2f(d[0]);
    float e1 = __builtin_amdgcn_exp2f(d[1]);
    float e2 = __builtin_amdgcn_exp2f(d[2]);
    float e3 = __builtin_amdgcn_exp2f(d[3]);
    half2 lo = __builtin_bit_cast(half2, __builtin_amdgcn_cvt_pkrtz(e0, e1));
    half2 hi = __builtin_bit_cast(half2, __builtin_amdgcn_cvt_pkrtz(e2, e3));
    half4 r = {lo[0], lo[1], hi[0], hi[1]};
    return r;
}

// one operand group: A-frag AF (16 j's) x 2 i-subtiles -> exp -> GEMM2 w/ PF frag.
// Keeps only 2 f32x4 d-temps live per group (register-pressure control).
#define GROUP(AF, PF_, B1A, B1B, ACCA, ACCB)                                         \
    {                                                                                \
        f32x4 _da = __builtin_amdgcn_mfma_f32_16x16x16f16(AF, B1A, zero, 0, 0, 0);   \
        f32x4 _db = __builtin_amdgcn_mfma_f32_16x16x16f16(AF, B1B, zero, 0, 0, 0);   \
        half4 _wa = expcvt(_da), _wb = expcvt(_db);                                  \
        ACCA = __builtin_amdgcn_mfma_f32_16x16x16f16(_wa, PF_, ACCA, 0, 0, 0);       \
        ACCB = __builtin_amdgcn_mfma_f32_16x16x16f16(_wb, PF_, ACCB, 0, 0, 0);       \
    }

// once per launch: aug features + softmax(unaries) -> pf0 (tiled); zero rows 10..15 both
__global__ __launch_bounds__(256) void init_kernel(
    const float* __restrict__ unaries, const float* __restrict__ feat,
    half8* __restrict__ ajs8, half8* __restrict__ ajb8,
    _Float16* __restrict__ pf0, _Float16* __restrict__ pf1) {
    int n = blockIdx.x * 256 + threadIdx.x;
    float f6[6];
#pragma unroll
    for (int d = 0; d < 6; ++d) f6[d] = feat[d * N + n];
    float h3 = 0.5f * (f6[0] * f6[0] + f6[1] * f6[1] + f6[2] * f6[2]);
    float h6v = h3 + 0.5f * (f6[3] * f6[3] + f6[4] * f6[4] + f6[5] * f6[5]);
    half8 a = {};
    a[0] = (_Float16)(f6[0] * C3);
    a[1] = (_Float16)(f6[1] * C3);
    a[2] = (_Float16)(f6[2] * C3);
    a[6] = (_Float16)(-h3 * C3);
    a[7] = (_Float16)1.0f;
    ajs8[n] = a;
    half8 b;
#pragma unroll
    for (int d = 0; d < 6; ++d) b[d] = (_Float16)(f6[d] * LOG2E);
    b[6] = (_Float16)(-h6v * LOG2E);
    b[7] = (_Float16)1.0f;
    ajb8[n] = b;

    float q[C];
#pragma unroll
    for (int c = 0; c < C; ++c) q[c] = unaries[c * N + n];
    float m = q[0];
#pragma unroll
    for (int c = 1; c < C; ++c) m = fmaxf(m, q[c]);
    float e[C], s = 0.0f;
#pragma unroll
    for (int c = 0; c < C; ++c) {
        e[c] = __builtin_amdgcn_exp2f((q[c] - m) * LOG2E);
        s += e[c];
    }
    float inv = 1.0f / s;
#pragma unroll
    for (int c = 0; c < C; ++c) pf0[PFIDX(n, c)] = (_Float16)(e[c] * inv);
#pragma unroll
    for (int c = C; c < 16; ++c) {
        pf0[PFIDX(n, c)] = (_Float16)0.0f;
        pf1[PFIDX(n, c)] = (_Float16)0.0f;
    }
}

// one dispatch per CRF iteration: block owns 32 i's; wave w free-runs its
// contiguous 512-j slice with DIRECT global->register operand fetch (coalesced,
// L2-resident, 1-deep prefetch). No LDS / no barriers in the main loop.
// LDS only for the final cross-wave reduction + in-block combine/softmax.
__global__ __launch_bounds__(FBLOCK, 4) void fused_kernel(
    const float* __restrict__ unaries, const float* __restrict__ feat,
    const float* __restrict__ SW, const float* __restrict__ BW,
    const float* __restrict__ CM,
    const half4* __restrict__ ajs_g, const half4* __restrict__ ajb_g,
    const _Float16* __restrict__ pf_in, _Float16* __restrict__ pf_out,
    float* __restrict__ out, int is_last) {
    __shared__ float rbuf[16 * 1024];   // 64 KB, epilogue only
    int t = threadIdx.x;
    int i0 = blockIdx.x * IBLK;
    int lane = t & 63;
    int w = t >> 6;            // wave id 0..15
    int il = lane & 15;
    int quad = lane >> 4;
    int h = quad & 1;
    bool klo = (quad < 2);
    const half4 hz = {};
    const f32x4 zero = {0.f, 0.f, 0.f, 0.f};

    // ---- i-side B1 fragments (32 i's, 2 subtiles of 16) ----
    half4 b1s0, b1s1, b1b0, b1b1;
#pragma unroll
    for (int s = 0; s < 2; ++s) {
        int i = i0 + s * 16 + il;
        float g0 = feat[0 * N + i], g1 = feat[1 * N + i], g2 = feat[2 * N + i];
        float g3 = feat[3 * N + i], g4 = feat[4 * N + i], g5 = feat[5 * N + i];
        float h3 = 0.5f * (g0 * g0 + g1 * g1 + g2 * g2);
        float h6v = h3 + 0.5f * (g3 * g3 + g4 * g4 + g5 * g5);
        half4 slo = {(_Float16)g0, (_Float16)g1, (_Float16)g2, (_Float16)0.0f};
        half4 shi = {(_Float16)0.0f, (_Float16)0.0f, (_Float16)1.0f, (_Float16)(-h3 * C3)};
        half4 blo = {(_Float16)g0, (_Float16)g1, (_Float16)g2, (_Float16)g3};
        half4 bhi = {(_Float16)g4, (_Float16)g5, (_Float16)1.0f, (_Float16)(-h6v * LOG2E)};
        half4 vs = klo ? (h ? shi : slo) : hz;
        half4 vb = klo ? (h ? bhi : blo) : hz;
        if (s == 0) { b1s0 = vs; b1b0 = vb; } else { b1s1 = vs; b1b1 = vb; }
    }

    f32x4 as0 = zero, as1 = zero, ab0 = zero, ab1 = zero;

    int jw = w * JW;   // wave's global j base
    // pf fragment pointer: tile jt holds p[c=il][j = jt*16 + quad*4 + r]
    const half4* pfv = (const half4*)pf_in;   // half4 index = (jt*16 + il)*4 + quad

    // ---- prologue: s-iter 0 operands (A-side garbage lanes quad>=2 are
    //      duplicated reals; safe since B1 is exactly zero for k>=8) ----
    half4 cvs0 = ajs_g[(jw + il) * 2 + h];
    half4 cvs1 = ajs_g[(jw + 16 + il) * 2 + h];
    half4 cvb0 = ajb_g[(jw + il) * 2 + h];
    half4 cvb1 = ajb_g[(jw + 16 + il) * 2 + h];
    half4 cp0 = pfv[((jw >> 4) * 16 + il) * 4 + quad];
    half4 cp1 = pfv[((jw >> 4) * 16 + 16 + il) * 4 + quad];

#pragma unroll 4
    for (int k = 0; k < NS; ++k) {
        int jn = jw + (((k + 1) & (NS - 1)) * 32);   // wrap: harmless reload
        half4 nvs0 = ajs_g[(jn + il) * 2 + h];
        half4 nvs1 = ajs_g[(jn + 16 + il) * 2 + h];
        half4 nvb0 = ajb_g[(jn + il) * 2 + h];
        half4 nvb1 = ajb_g[(jn + 16 + il) * 2 + h];
        half4 np0 = pfv[((jn >> 4) * 16 + il) * 4 + quad];
        half4 np1 = pfv[((jn >> 4) * 16 + 16 + il) * 4 + quad];

        GROUP(cvs0, cp0, b1s0, b1s1, as0, as1);   // spatial, j 0..15
        GROUP(cvs1, cp1, b1s0, b1s1, as0, as1);   // spatial, j 16..31
        GROUP(cvb0, cp0, b1b0, b1b1, ab0, ab1);   // bilateral, j 0..15
        GROUP(cvb1, cp1, b1b0, b1b1, ab0, ab1);   // bilateral, j 16..31

        cvs0 = nvs0; cvs1 = nvs1; cvb0 = nvb0; cvb1 = nvb1;
        cp0 = np0; cp1 = np1;
    }

    // ---- cross-wave reduction in LDS (conflict-free dump: r*64+lane) ----
    {
        float* rb = rbuf + w * 1024;
#pragma unroll
        for (int r = 0; r < 4; ++r) {
            rb[r * 64 + lane]       = as0[r];
            rb[256 + r * 64 + lane] = as1[r];
            rb[512 + r * 64 + lane] = ab0[r];
            rb[768 + r * 64 + lane] = ab1[r];
        }
    }
    __syncthreads();
    {
        float tot = 0.f;
#pragma unroll
        for (int w2 = 0; w2 < 16; ++w2) tot += rbuf[w2 * 1024 + t];
        rbuf[t] = tot;   // w2=0 slot: read/written only by this thread
    }
    __syncthreads();

    // ---- combine + compatibility + softmax for this block's 32 i's ----
    if (t < IBLK) {
        int i = i0 + t;
        int sub = t >> 4, ql = (t & 15) >> 2, rr = t & 3;
        float sp[C], bl[C];
#pragma unroll
        for (int c = 0; c < C; ++c) {
            int base = sub * 256 + rr * 64 + ql * 16 + c;
            sp[c] = rbuf[base];
            bl[c] = rbuf[base + 512];
        }
        float msg[C];
#pragma unroll
        for (int c = 0; c < C; ++c) {
            float m = 0.f;
#pragma unroll
            for (int k = 0; k < C; ++k)
                m += SW[c * C + k] * sp[k] + BW[c * C + k] * bl[k];
            msg[c] = m;
        }
        float qq[C];
#pragma unroll
        for (int c = 0; c < C; ++c) {
            float pw = 0.f;
#pragma unroll
            for (int k = 0; k < C; ++k) pw += CM[c * C + k] * msg[k];
            qq[c] = unaries[c * N + i] - pw;
        }
        if (is_last) {
#pragma unroll
            for (int c = 0; c < C; ++c) out[c * N + i] = qq[c];
        } else {
            float m = qq[0];
#pragma unroll
            for (int c = 1; c < C; ++c) m = fmaxf(m, qq[c]);
            float e[C], s = 0.0f;
#pragma unroll
            for (int c = 0; c < C; ++c) {
                e[c] = __builtin_amdgcn_exp2f((qq[c] - m) * LOG2E);
                s += e[c];
            }
            float inv = 1.0f / s;
#pragma unroll
            for (int c = 0; c < C; ++c) pf_out[PFIDX(i, c)] = (_Float16)(e[c] * inv);
        }
    }
}

extern "C" void kernel_launch(void* const* d_in, const int* in_sizes, int n_in,
                              void* d_out, int out_size, void* d_ws, size_t ws_size,
                              hipStream_t stream) {
    const float* unaries = (const float*)d_in[0];   // [10, 8192]
    const float* feat    = (const float*)d_in[1];   // [6, 8192]
    const float* SW      = (const float*)d_in[2];   // [10,10]
    const float* BW      = (const float*)d_in[3];   // [10,10]
    const float* CM      = (const float*)d_in[4];   // [10,10]
    float* out = (float*)d_out;

    char* ws = (char*)d_ws;
    half8* ajs    = (half8*)(ws + WS_AJS);
    half8* ajb    = (half8*)(ws + WS_AJB);
    _Float16* pf0 = (_Float16*)(ws + WS_PF0);
    _Float16* pf1 = (_Float16*)(ws + WS_PF1);

    init_kernel<<<N / 256, 256, 0, stream>>>(unaries, feat, ajs, ajb, pf0, pf1);
    const _Float16* pin = pf0;
    _Float16* pout = pf1;
    for (int it = 1; it <= NUM_ITERS; ++it) {
        fused_kernel<<<NBLK, FBLOCK, 0, stream>>>(
            unaries, feat, SW, BW, CM, (const half4*)ajs, (const half4*)ajb,
            pin, pout, out, it == NUM_ITERS ? 1 : 0);
        const _Float16* tmp = pout;
        pout = (_Float16*)pin;
        pin = tmp;
    }
}